// Round 1
// baseline (128.589 us; speedup 1.0000x reference)
//
#include <hip/hip_runtime.h>
#include <hip/hip_bf16.h>
#include <stdint.h>

// Problem constants (B=1)
#define NN   256     // MSA depth (contraction K of GEMM1)
#define LL   192
#define MDIM 6144    // L*J
#define D2   1024    // J*J
#define FF   128     // n_feat_out

typedef __bf16 bf16x8 __attribute__((ext_vector_type(8)));
typedef float  f32x4  __attribute__((ext_vector_type(4)));

#define MFMA16(a, b, c) __builtin_amdgcn_mfma_f32_16x16x32_bf16(a, b, c, 0, 0, 0)

__device__ __forceinline__ void gload_lds16(const void* g, void* l) {
  __builtin_amdgcn_global_load_lds(
      (__attribute__((address_space(1))) void*)(g),
      (__attribute__((address_space(3))) void*)(l),
      16, 0, 0);
}

static __device__ __forceinline__ unsigned short bf16_bits(float v) {
  __bf16 h = (__bf16)v;
  return __builtin_bit_cast(unsigned short, h);
}

// ---------------------------------------------------------------------------
// Unified prep (one launch) — UNCHANGED from the verified kernel:
//  blocks [0,1536):    transpose x_down  [256][6144] f32 -> At [6144][256] bf16
//  blocks [1536,3072): transpose x_down_w            -> Bt
//  blocks [3072,3200): WB[fragment-linear] = bf16(a2*W), S = colsum, T = b2@W+b
// ---------------------------------------------------------------------------
__global__ __launch_bounds__(256)
void prep_all(const float* __restrict__ x1, const float* __restrict__ x2,
              const float* __restrict__ W, const float* __restrict__ a2,
              const float* __restrict__ b2, const float* __restrict__ bias,
              __bf16* __restrict__ At, __bf16* __restrict__ Bt,
              __bf16* __restrict__ WB, float* __restrict__ S,
              float* __restrict__ T) {
  __shared__ float tile[32][33];
  const int b = blockIdx.x;
  const int t = threadIdx.x;
  if (b < 3072) {
    const float* src = (b < 1536) ? x1 : x2;
    __bf16* dst = (b < 1536) ? At : Bt;
    const int bb = (b < 1536) ? b : b - 1536;
    const int m0 = (bb % 192) * 32;
    const int k0 = (bb / 192) * 32;
    {
      const int kr = t >> 3, mc = (t & 7) * 4;
      const float4 v = *(const float4*)&src[(size_t)(k0 + kr) * MDIM + m0 + mc];
      tile[kr][mc + 0] = v.x;
      tile[kr][mc + 1] = v.y;
      tile[kr][mc + 2] = v.z;
      tile[kr][mc + 3] = v.w;
    }
    __syncthreads();
    {
      const int mr = t >> 3, kc = (t & 7) * 4;
      ushort4 u;
      u.x = bf16_bits(tile[kc + 0][mr]);
      u.y = bf16_bits(tile[kc + 1][mr]);
      u.z = bf16_bits(tile[kc + 2][mr]);
      u.w = bf16_bits(tile[kc + 3][mr]);
      *(ushort4*)&dst[(size_t)(m0 + mr) * NN + k0 + kc] = u;
    }
  } else {
    const int f = b - 3072;
    float s = 0.f, tt = 0.f;
#pragma unroll
    for (int it = 0; it < 4; ++it) {
      const int k = t + it * 256;
      const float wv = W[(size_t)k * FF + f];
      const __bf16 wa = (__bf16)(a2[k] * wv);
      WB[(size_t)(k >> 5) * 4096 + f * 32 + ((k >> 3) & 3) * 8 + (k & 7)] = wa;
      s += (float)wa;
      tt += b2[k] * wv;
    }
#pragma unroll
    for (int off = 32; off; off >>= 1) {
      s += __shfl_xor(s, off);
      tt += __shfl_xor(tt, off);
    }
    const int wv_ = t >> 6, ln = t & 63;
    if (ln == 0) { tile[0][wv_] = s; tile[1][wv_] = tt; }
    __syncthreads();
    if (t == 0) {
      S[f] = tile[0][0] + tile[0][1] + tile[0][2] + tile[0][3];
      T[f] = tile[1][0] + tile[1][1] + tile[1][2] + tile[1][3] + bias[f];
    }
  }
}

// ---------------------------------------------------------------------------
// fused11: 256x256 tile / 1024 threads (16 waves), 576 blocks.
// Changes vs fused10 (124.9us total, fused 53.4us):
//  - L2-read cut: 510MB -> 295MB (staging 221->147MB: half the blocks;
//    WB 288->147MB: GEMM2 done by 8 waves x 16f x all-64-rows so WB is read
//    once per block).
//  - GEMM1 overlap: double-buffered BK=64 staging (2x64KB, aliased with the
//    128KB Xs), guide-minimum 2-phase schedule with RAW s_barrier + counted
//    s_waitcnt vmcnt(4) (never drain-0 mid-loop) so stage(k+1) L2 latency
//    hides under compute(k). fused10 was fully serial load->drain->compute.
//  - Per-wave GEMM1 code (64x64 slice, 128B-row XOR swizzle) and the LN
//    scatter/GEMM2 fragment math are copied verbatim from the proven kernel;
//    only geometry indices changed (wave grid 4x4, LN rows 64, i = bx*8+..).
//  - Occupancy: 1 block/CU = 16 waves/CU = 4/SIMD, same as before.
//    __launch_bounds__(1024,4): same 128-reg/thread budget fused10 proved
//    spill-free. Spill tripwire: WRITE_SIZE == 18432 KB exactly.
//  - Banding: 576 = 8 XCDs x (6bx x 12by); band = 768KB A + 1.5MB B + 256KB
//    WB = 2.5MB < 4MB L2/XCD.
// out = rstd*(x@Wa - mean*S) + T
// ---------------------------------------------------------------------------
__global__ __launch_bounds__(1024, 4)
void fused11(const __bf16* __restrict__ At, const __bf16* __restrict__ Bt,
             const __bf16* __restrict__ WB, const float* __restrict__ S,
             const float* __restrict__ T, float* __restrict__ out) {
  extern __shared__ uint8_t lds[];   // 131072 B: staging dbuf / Xs[64][2048]
  __shared__ float mean_s[64], rstd_s[64];

  const int tid = threadIdx.x;
  const int w = tid >> 6;            // wave 0..15
  const int lane = tid & 63;
  const int q = lane >> 4;           // quad
  const int c = lane & 15;

  // ---- XCD banding: b&7 = XCD (round-robin dispatch), 6x12 rectangle ----
  const int b = blockIdx.x;
  const int xcd = b & 7;
  const int s_ = b >> 3;                        // 0..71
  const int bx = (xcd >> 1) * 6 + (s_ % 6);     // 0..23  (m, 256-wide)
  const int by = (xcd & 1) * 12 + (s_ / 6);     // 0..23  (n, 256-wide)
  const int m0 = bx * 256, n0 = by * 256;

  // double-buffered staging: each buffer = A 32KB + B 32KB
  uint8_t* As0 = lds;                // 256 rows x 128B
  uint8_t* Bs0 = lds + 32768;
  uint8_t* As1 = lds + 65536;
  uint8_t* Bs1 = lds + 98304;

  // staging lane decomposition: 8 lanes per 128B row (BK=64 bf16)
  const int l8 = lane & 7;
  const int r8 = lane >> 3;
  const int gsw = l8 ^ r8;           // XOR-swizzled source 16B-group

  f32x4 acc[4][4];
#pragma unroll
  for (int i = 0; i < 4; ++i)
#pragma unroll
    for (int j = 0; j < 4; ++j)
      acc[i][j] = (f32x4){0.f, 0.f, 0.f, 0.f};

  const int mbase = (w & 3) * 64;    // wave grid 4(m) x 4(n)
  const int nbase = (w >> 2) * 64;

  // ------------- GEMM1 K-loop: 4 chunks of BK=64, 2-phase dbuf -------------
  const __bf16* gA = At + (size_t)(m0 + w * 16 + r8) * NN + gsw * 8;
  const __bf16* gB = Bt + (size_t)(n0 + w * 16 + r8) * NN + gsw * 8;

  // prologue: stage chunk 0 into buffer 0 (A: 16 rows/wave, B: 16 rows/wave)
#pragma unroll
  for (int j = 0; j < 2; ++j)
    gload_lds16(gA + (size_t)j * 8 * NN, As0 + (w * 16 + j * 8) * 128);
#pragma unroll
  for (int j = 0; j < 2; ++j)
    gload_lds16(gB + (size_t)j * 8 * NN, Bs0 + (w * 16 + j * 8) * 128);

#pragma unroll
  for (int kb = 0; kb < 4; ++kb) {
    uint8_t* Ac = (kb & 1) ? As1 : As0;
    uint8_t* Bc = (kb & 1) ? Bs1 : Bs0;
    if (kb < 3) {
      // issue stage(kb+1) into the other buffer; its last readers finished
      // before the barrier that ended iter kb-1.
      uint8_t* An = (kb & 1) ? As0 : As1;
      uint8_t* Bn = (kb & 1) ? Bs0 : Bs1;
      const __bf16* ga = gA + (size_t)(kb + 1) * 64;
      const __bf16* gb = gB + (size_t)(kb + 1) * 64;
#pragma unroll
      for (int j = 0; j < 2; ++j)
        gload_lds16(ga + (size_t)j * 8 * NN, An + (w * 16 + j * 8) * 128);
#pragma unroll
      for (int j = 0; j < 2; ++j)
        gload_lds16(gb + (size_t)j * 8 * NN, Bn + (w * 16 + j * 8) * 128);
      // counted: 4 just-issued stay in flight; waits only stage(kb)'s 4.
      asm volatile("s_waitcnt vmcnt(4)" ::: "memory");
    } else {
      asm volatile("s_waitcnt vmcnt(0)" ::: "memory");
    }
    __builtin_amdgcn_s_barrier();    // all waves' stage(kb) landed
    __builtin_amdgcn_sched_barrier(0);
#pragma unroll
    for (int ks = 0; ks < 2; ++ks) {
      const int slot = ((ks * 4 + q) ^ l8) * 16;
      bf16x8 a[4];
#pragma unroll
      for (int t4 = 0; t4 < 4; ++t4)
        a[t4] = *(const bf16x8*)(Ac + (mbase + t4 * 16 + c) * 128 + slot);
#pragma unroll
      for (int tj = 0; tj < 4; ++tj) {
        const bf16x8 bfr =
            *(const bf16x8*)(Bc + (nbase + tj * 16 + c) * 128 + slot);
#pragma unroll
        for (int ti = 0; ti < 4; ++ti)
          acc[ti][tj] = MFMA16(a[ti], bfr, acc[ti][tj]);
      }
    }
    // all of this wave's ds_reads of buf[kb] done, then rendezvous: next
    // iteration may overwrite buf[kb] (and after kb=3, Xs aliases everything).
    asm volatile("s_waitcnt lgkmcnt(0)" ::: "memory");
    __builtin_amdgcn_s_barrier();
  }

  // ------------- GEMM2 depth-2 prefetch (held shallow while acc is live) ----
  const int fs = w * 16;             // f-slice (meaningful for w<8)
  const __bf16* wbp = WB + (fs + c) * 32 + q * 8;   // + kstep*4096 elements
  bf16x8 pb[8];
  if (w < 8) {
    pb[0] = *(const bf16x8*)(wbp);
    pb[1] = *(const bf16x8*)(wbp + 4096);
  }

  // ------------- LN stats (in-wave) + packed-b32 swizzled scatter -------------
  // Xs byte addr for element (row r, k): g=k>>3; G = g ^ (g>>4) ^ (r&7);
  // addr = r*2048 + G*16 + (k&7)*2
  const int i_hi = w & 3, l_hi = w >> 2;   // i_local = i_hi*2+ab, l_local = l_hi*2+cb
#pragma unroll
  for (int ab = 0; ab < 2; ++ab) {
#pragma unroll
    for (int cb = 0; cb < 2; ++cb) {
      float s1 = 0.f, s2 = 0.f;
#pragma unroll
      for (int dti = 0; dti < 2; ++dti)
#pragma unroll
        for (int dtj = 0; dtj < 2; ++dtj)
#pragma unroll
          for (int reg = 0; reg < 4; ++reg) {
            const float v = acc[ab * 2 + dti][cb * 2 + dtj][reg];
            s1 += v; s2 += v * v;
          }
#pragma unroll
      for (int off = 32; off; off >>= 1) {
        s1 += __shfl_xor(s1, off);
        s2 += __shfl_xor(s2, off);
      }
      const float mean = s1 * (1.0f / 1024.0f);
      const float var = s2 * (1.0f / 1024.0f) - mean * mean;
      const float rstd = rsqrtf(var + 1e-5f);
      const int r = (i_hi * 2 + ab) * 8 + l_hi * 2 + cb;   // 0..63
      if (lane == 0) { mean_s[r] = mean; rstd_s[r] = rstd; }
      const int r7 = r & 7;
#pragma unroll
      for (int dti = 0; dti < 2; ++dti)
#pragma unroll
        for (int dtj = 0; dtj < 2; ++dtj)
#pragma unroll
          for (int rp = 0; rp < 4; rp += 2) {
            const float x = acc[ab * 2 + dti][cb * 2 + dtj][rp];
            const float y = acc[ab * 2 + dti][cb * 2 + dtj][rp + 1];
            const float send = (c & 1) ? x : y;
            const float recv = __shfl_xor(send, 1);
            const float vlo = (c & 1) ? recv : x;
            const float vhi = (c & 1) ? y : recv;
            const int reg_w = (c & 1) ? rp + 1 : rp;
            const int j = dti * 16 + q * 4 + reg_w;
            const int mm0 = dtj * 16 + (c & ~1);
            const int k = j * 32 + mm0;
            const int g = k >> 3;
            const int G = g ^ (g >> 4) ^ r7;
            const uint32_t dw =
                ((uint32_t)bf16_bits(vhi) << 16) | (uint32_t)bf16_bits(vlo);
            *(uint32_t*)(lds + r * 2048 + G * 16 + (mm0 & 7) * 2) = dw;
          }
    }
  }

  __syncthreads();   // Xs + stats visible; acc DEAD below

  // ------------- GEMM2: Xs(64x1024) @ Wa^T, 8 waves x 16f x 64 rows ---------
  // WB read ONCE per block (147MB total vs fused10's 288MB). Waves 8..15 done.
  if (w < 8) {
    __builtin_amdgcn_sched_barrier(0);   // pin the deepening loads below
#pragma unroll
    for (int p = 2; p < 8; ++p)
      pb[p] = *(const bf16x8*)(wbp + p * 4096);

    f32x4 acc2[4];
#pragma unroll
    for (int rr = 0; rr < 4; ++rr) acc2[rr] = (f32x4){0.f, 0.f, 0.f, 0.f};
    const int c7 = c & 7;
#pragma unroll
    for (int kstep = 0; kstep < 32; ++kstep) {
      const int g = kstep * 4 + q;
      const int G = g ^ (g >> 4) ^ c7;
      const bf16x8 a0 = *(const bf16x8*)(lds + (size_t)(c)      * 2048 + G * 16);
      const bf16x8 a1 = *(const bf16x8*)(lds + (size_t)(16 + c) * 2048 + G * 16);
      const bf16x8 a2 = *(const bf16x8*)(lds + (size_t)(32 + c) * 2048 + G * 16);
      const bf16x8 a3 = *(const bf16x8*)(lds + (size_t)(48 + c) * 2048 + G * 16);
      acc2[0] = MFMA16(a0, pb[kstep & 7], acc2[0]);
      acc2[1] = MFMA16(a1, pb[kstep & 7], acc2[1]);
      acc2[2] = MFMA16(a2, pb[kstep & 7], acc2[2]);
      acc2[3] = MFMA16(a3, pb[kstep & 7], acc2[3]);
      if (kstep < 24)
        pb[kstep & 7] = *(const bf16x8*)(wbp + (kstep + 8) * 4096);
    }

    // ------------- epilogue: affine + store (S/T loaded only now) -----------
    const float S0 = S[fs + c], T0 = T[fs + c];
#pragma unroll
    for (int rr = 0; rr < 4; ++rr)
#pragma unroll
      for (int reg = 0; reg < 4; ++reg) {
        const int r = rr * 16 + q * 4 + reg;     // LN row 0..63
        const float mean = mean_s[r], rstd = rstd_s[r];
        const int i = bx * 8 + (r >> 3);
        const int l = by * 8 + (r & 7);
        out[((size_t)i * LL + l) * FF + fs + c] =
            rstd * (acc2[rr][reg] - mean * S0) + T0;
      }
  }
}

// ---------------------------------------------------------------------------
extern "C" void kernel_launch(void* const* d_in, const int* in_sizes, int n_in,
                              void* d_out, int out_size, void* d_ws, size_t ws_size,
                              hipStream_t stream) {
  const float* x_down   = (const float*)d_in[0];
  const float* x_down_w = (const float*)d_in[1];
  const float* a2       = (const float*)d_in[2];
  const float* b2       = (const float*)d_in[3];
  const float* W        = (const float*)d_in[4];
  const float* bias     = (const float*)d_in[5];
  float* out = (float*)d_out;

  uint8_t* ws = (uint8_t*)d_ws;
  __bf16* At  = (__bf16*)(ws);                 // 6144*256*2 = 3145728 B
  __bf16* Bt  = (__bf16*)(ws + 3145728);       // 3145728 B
  __bf16* WB  = (__bf16*)(ws + 6291456);       // 128*1024*2 = 262144 B
  float*  S   = (float*)(ws + 6553600);        // 512 B
  float*  T   = (float*)(ws + 6554112);        // 512 B

  hipFuncSetAttribute((const void*)fused11,
                      hipFuncAttributeMaxDynamicSharedMemorySize, 131072);

  prep_all<<<dim3(3200), dim3(256), 0, stream>>>(x_down, x_down_w, W, a2, b2,
                                                 bias, At, Bt, WB, S, T);
  fused11<<<dim3(576), dim3(1024), 131072, stream>>>(At, Bt, WB, S, T, out);
}